// Round 5
// baseline (537.209 us; speedup 1.0000x reference)
//
#include <hip/hip_runtime.h>

#define T_DIM 1024
#define B_DIM 16
#define D_DIM 512
#define K_W   31
#define PAD   15

// ===========================================================================
// ALL numeric ops are f32 with NO fma contraction and numpy-sequential
// reduction order, to bit-match a naive numpy float32 transcription of the
// reference (the harness's `ref=np`). Do NOT "improve" precision here: f64
// accuracy FLIPS a borderline spike vs the f32 np ref (rounds 1-4, absmax
// 0.998046875 every time).
// ===========================================================================

// ---------------------------------------------------------------------------
// K1: pointwise GEMM, f32, strict d-ascending accumulation, no FMA.
//   Y[b][tau - tau0][e] = (sum_{d=0..511} w_pw[e][d] * inp[tau][b][d]) + b_pw[e]
// Output layout (B, NTW, E), e-contiguous.
// ---------------------------------------------------------------------------
__global__ __launch_bounds__(256, 2)
void pw_gemm(const float* __restrict__ inp, const float* __restrict__ w_pw,
             const float* __restrict__ b_pw, float* __restrict__ Yw,
             int tau0, int tau1, int NTW)
{
#pragma clang fp contract(off)
    __shared__ float Es[32 * 128];   // [k][e_local]
    __shared__ float Ts[32 * 128];   // [k][tau_local]

    const int tid = threadIdx.x;
    const int e0  = blockIdx.x * 128;
    int tg0 = tau0 + blockIdx.y * 128;           // tau tile base
    if (tg0 + 128 > tau1) {                      // shift last tile; overlap
        int s = tau1 - 128;                      // writes identical values
        tg0 = (s > tau0) ? s : tau0;
    }
    const int b  = blockIdx.z;
    const int rt = tid >> 4;                     // tau-sub 0..15
    const int ce = tid & 15;                     // e-sub   0..15

    float acc[8][8];
#pragma unroll
    for (int i = 0; i < 8; ++i)
#pragma unroll
        for (int j = 0; j < 8; ++j) acc[i][j] = 0.0f;

    for (int k0 = 0; k0 < D_DIM; k0 += 32) {     // strict ascending d blocks
        float4 av[4], xv[4];
#pragma unroll
        for (int i = 0; i < 4; ++i) {
            int cid = tid + 256 * i;             // 0..1023
            int row = cid >> 3;                  // 0..127
            int kq  = cid & 7;
            int trow = tg0 + row;
            if (trow > T_DIM - 1) trow = T_DIM - 1;   // clamp; stores guarded
            av[i] = *(const float4*)&w_pw[(size_t)(e0 + row) * D_DIM + k0 + kq * 4];
            xv[i] = *(const float4*)&inp[(size_t)trow * (B_DIM * D_DIM)
                                         + (size_t)b * D_DIM + k0 + kq * 4];
        }
        __syncthreads();
#pragma unroll
        for (int i = 0; i < 4; ++i) {
            int cid = tid + 256 * i;
            int row = cid >> 3;
            int kq  = cid & 7;
            Es[(kq * 4 + 0) * 128 + row] = av[i].x;
            Es[(kq * 4 + 1) * 128 + row] = av[i].y;
            Es[(kq * 4 + 2) * 128 + row] = av[i].z;
            Es[(kq * 4 + 3) * 128 + row] = av[i].w;
            Ts[(kq * 4 + 0) * 128 + row] = xv[i].x;
            Ts[(kq * 4 + 1) * 128 + row] = xv[i].y;
            Ts[(kq * 4 + 2) * 128 + row] = xv[i].z;
            Ts[(kq * 4 + 3) * 128 + row] = xv[i].w;
        }
        __syncthreads();

#pragma unroll 8
        for (int kk = 0; kk < 32; ++kk) {        // strict ascending d
            float4 tf0 = *(const float4*)&Ts[kk * 128 + rt * 8];
            float4 tf1 = *(const float4*)&Ts[kk * 128 + rt * 8 + 4];
            float4 ef0 = *(const float4*)&Es[kk * 128 + ce * 8];
            float4 ef1 = *(const float4*)&Es[kk * 128 + ce * 8 + 4];
            float a[8] = {tf0.x, tf0.y, tf0.z, tf0.w, tf1.x, tf1.y, tf1.z, tf1.w};
            float x[8] = {ef0.x, ef0.y, ef0.z, ef0.w, ef1.x, ef1.y, ef1.z, ef1.w};
#pragma unroll
            for (int i = 0; i < 8; ++i)
#pragma unroll
                for (int j = 0; j < 8; ++j)
                    acc[i][j] = __fadd_rn(acc[i][j], __fmul_rn(a[i], x[j]));
        }
    }

    float bias[8];
#pragma unroll
    for (int j = 0; j < 8; ++j) bias[j] = b_pw[e0 + ce * 8 + j];

#pragma unroll
    for (int i = 0; i < 8; ++i) {
        int tau = tg0 + rt * 8 + i;
        if (tau < tau1) {
            float* yrow = Yw + ((size_t)b * NTW + (tau - tau0)) * D_DIM + e0 + ce * 8;
#pragma unroll
            for (int j = 0; j < 8; ++j)
                yrow[j] = __fadd_rn(acc[i][j], bias[j]);
        }
    }
}

// ---------------------------------------------------------------------------
// K2: depthwise conv, f32, strict k-ascending, no FMA, zero padding.
//   Z[(t-t0)][b][d] = sum_{k=0..30} w_dw[d][k] * Y[b][t-15+k][d]
// ---------------------------------------------------------------------------
__global__ __launch_bounds__(512, 1)
void dw_conv(const float* __restrict__ Yw, const float* __restrict__ w_dw,
             float* __restrict__ Zw, int t0, int tau0, int NTW)
{
#pragma clang fp contract(off)
    const int d  = threadIdx.x;              // 0..511
    const int tb = blockIdx.x * 8;           // t offset within pass
    const int b  = blockIdx.y;

    float wd[K_W];
#pragma unroll
    for (int k = 0; k < K_W; ++k) wd[k] = w_dw[d * K_W + k];

    const float* ybase = Yw + (size_t)b * NTW * D_DIM + d;

    float yw[38];
#pragma unroll
    for (int i = 0; i < 38; ++i) {
        int tau = t0 + tb - PAD + i;
        yw[i] = (tau >= 0 && tau < T_DIM)
              ? ybase[(size_t)(tau - tau0) * D_DIM] : 0.0f;
    }

#pragma unroll
    for (int j = 0; j < 8; ++j) {
        float z = 0.0f;
#pragma unroll
        for (int k = 0; k < K_W; ++k)        // strict ascending k
            z = __fadd_rn(z, __fmul_rn(wd[k], yw[j + k]));
        Zw[((size_t)(tb + j) * B_DIM + b) * D_DIM + d] = z;
    }
}

// ---------------------------------------------------------------------------
// K3: EXACT sequential LIF scan + residual, f32, numpy op-for-op:
//   v = fl(fl(v*0.5) + z); s = (v >= 1); out = fl(s + x); v = fl(v*(1-s))
// One thread per (b,d); v carried across passes via vst.
// ---------------------------------------------------------------------------
__global__ __launch_bounds__(64, 1)
void lif_scan(const float* __restrict__ Zw, const float* __restrict__ inp,
              float* __restrict__ out, float* __restrict__ vst,
              int t0, int L, int first)
{
#pragma clang fp contract(off)
    const int lane = threadIdx.x;
    const int b    = blockIdx.x >> 3;                 // 0..15
    const int d    = ((blockIdx.x & 7) << 6) + lane;  // 0..511
    const int gi   = b * D_DIM + d;

    float v = first ? 0.0f : vst[gi];

    const float* zp = Zw + (size_t)b * D_DIM + d;
    const float* ip = inp + ((size_t)t0 * B_DIM + b) * D_DIM + d;
    float*       op = out + ((size_t)t0 * B_DIM + b) * D_DIM + d;
    const size_t st = (size_t)B_DIM * D_DIM;

    float zbuf[16];
    float xbuf[16];
#pragma unroll
    for (int j = 0; j < 16; ++j) {
        zbuf[j] = zp[(size_t)j * st];
        xbuf[j] = ip[(size_t)j * st];
    }

    for (int tb = 0; tb < L; tb += 16) {
#pragma unroll
        for (int j = 0; j < 16; ++j) {          // static j -> regs, no scratch
            const int t = tb + j;
            const float z = zbuf[j];
            const float x = xbuf[j];
            const int tn = t + 16;
            if (tn < L) {                       // prefetch slot j for t+16
                zbuf[j] = zp[(size_t)tn * st];
                xbuf[j] = ip[(size_t)tn * st];
            }
            v = __fadd_rn(__fmul_rn(v, 0.5f), z);
            const bool sp = (v >= 1.0f);
            op[(size_t)t * st] = __fadd_rn(sp ? 1.0f : 0.0f, x);
            v = __fmul_rn(v, sp ? 0.0f : 1.0f); // mirrors np v*(1-s) incl. -0
        }
    }
    vst[gi] = v;
}

// ---------------------------------------------------------------------------
// Pass-windowed driver (f32 buffers: Y NTW rows + Z L rows + vst, row=32KB).
// L chosen from ws_size (launch-time constant -> deterministic).
// ---------------------------------------------------------------------------
extern "C" void kernel_launch(void* const* d_in, const int* in_sizes, int n_in,
                              void* d_out, int out_size, void* d_ws, size_t ws_size,
                              hipStream_t stream)
{
    const float* inp  = (const float*)d_in[0];   // (T,B,D)
    const float* w_pw = (const float*)d_in[1];   // (D,D)
    const float* b_pw = (const float*)d_in[2];   // (D)
    const float* w_dw = (const float*)d_in[3];   // (D,K)
    float* out = (float*)d_out;

    auto need = [](int L) -> size_t {
        int ntw = (L + 30 > T_DIM) ? T_DIM : (L + 30);
        return ((size_t)ntw + (size_t)L + 1) * (B_DIM * D_DIM * sizeof(float));
    };
    int L = 32;
    if      (ws_size >= need(1024)) L = 1024;
    else if (ws_size >= need(512))  L = 512;
    else if (ws_size >= need(256))  L = 256;
    else if (ws_size >= need(128))  L = 128;
    else if (ws_size >= need(64))   L = 64;

    const int NTWmax = (L + 30 > T_DIM) ? T_DIM : (L + 30);
    float* Yw  = (float*)d_ws;
    float* Zw  = Yw + (size_t)NTWmax * B_DIM * D_DIM;
    float* vst = Zw + (size_t)L * B_DIM * D_DIM;

    const int P = T_DIM / L;
    for (int p = 0; p < P; ++p) {
        const int t0   = p * L;
        const int t1   = t0 + L;
        const int tau0 = (t0 - PAD > 0) ? (t0 - PAD) : 0;
        const int tau1 = (t1 + PAD < T_DIM) ? (t1 + PAD) : T_DIM;
        const int NTW  = tau1 - tau0;

        dim3 g1(D_DIM / 128, (NTW + 127) / 128, B_DIM);
        pw_gemm<<<g1, 256, 0, stream>>>(inp, w_pw, b_pw, Yw, tau0, tau1, NTW);

        dim3 g2(L / 8, B_DIM);
        dw_conv<<<g2, 512, 0, stream>>>(Yw, w_dw, Zw, t0, tau0, NTW);

        lif_scan<<<128, 64, 0, stream>>>(Zw, inp, out, vst, t0, L, p == 0);
    }
}

// Round 6
// 243.035 us; speedup vs baseline: 2.2104x; 2.2104x over previous
//
#include <hip/hip_runtime.h>

#define T_DIM 1024
#define B_DIM 16
#define D_DIM 512
#define K_W   31
#define PAD   15

// ===========================================================================
// ALL numeric ops are f32 with NO fma contraction and numpy-sequential
// reduction order, to bit-match the harness's strict-sequential f32 np ref.
// Round 5 PASSED with absmax 0.0 — do NOT change rounding/order/precision:
// f64 accuracy FLIPS a borderline spike (rounds 1-4, absmax 0.998046875).
// ===========================================================================

// ---------------------------------------------------------------------------
// K1: pointwise GEMM, f32, strict d-ascending accumulation, no FMA.
// (byte-identical to round 5 — proven bit-exact)
// ---------------------------------------------------------------------------
__global__ __launch_bounds__(256, 2)
void pw_gemm(const float* __restrict__ inp, const float* __restrict__ w_pw,
             const float* __restrict__ b_pw, float* __restrict__ Yw,
             int tau0, int tau1, int NTW)
{
#pragma clang fp contract(off)
    __shared__ float Es[32 * 128];   // [k][e_local]
    __shared__ float Ts[32 * 128];   // [k][tau_local]

    const int tid = threadIdx.x;
    const int e0  = blockIdx.x * 128;
    int tg0 = tau0 + blockIdx.y * 128;           // tau tile base
    if (tg0 + 128 > tau1) {                      // shift last tile; overlap
        int s = tau1 - 128;                      // writes identical values
        tg0 = (s > tau0) ? s : tau0;
    }
    const int b  = blockIdx.z;
    const int rt = tid >> 4;                     // tau-sub 0..15
    const int ce = tid & 15;                     // e-sub   0..15

    float acc[8][8];
#pragma unroll
    for (int i = 0; i < 8; ++i)
#pragma unroll
        for (int j = 0; j < 8; ++j) acc[i][j] = 0.0f;

    for (int k0 = 0; k0 < D_DIM; k0 += 32) {     // strict ascending d blocks
        float4 av[4], xv[4];
#pragma unroll
        for (int i = 0; i < 4; ++i) {
            int cid = tid + 256 * i;             // 0..1023
            int row = cid >> 3;                  // 0..127
            int kq  = cid & 7;
            int trow = tg0 + row;
            if (trow > T_DIM - 1) trow = T_DIM - 1;   // clamp; stores guarded
            av[i] = *(const float4*)&w_pw[(size_t)(e0 + row) * D_DIM + k0 + kq * 4];
            xv[i] = *(const float4*)&inp[(size_t)trow * (B_DIM * D_DIM)
                                         + (size_t)b * D_DIM + k0 + kq * 4];
        }
        __syncthreads();
#pragma unroll
        for (int i = 0; i < 4; ++i) {
            int cid = tid + 256 * i;
            int row = cid >> 3;
            int kq  = cid & 7;
            Es[(kq * 4 + 0) * 128 + row] = av[i].x;
            Es[(kq * 4 + 1) * 128 + row] = av[i].y;
            Es[(kq * 4 + 2) * 128 + row] = av[i].z;
            Es[(kq * 4 + 3) * 128 + row] = av[i].w;
            Ts[(kq * 4 + 0) * 128 + row] = xv[i].x;
            Ts[(kq * 4 + 1) * 128 + row] = xv[i].y;
            Ts[(kq * 4 + 2) * 128 + row] = xv[i].z;
            Ts[(kq * 4 + 3) * 128 + row] = xv[i].w;
        }
        __syncthreads();

#pragma unroll 8
        for (int kk = 0; kk < 32; ++kk) {        // strict ascending d
            float4 tf0 = *(const float4*)&Ts[kk * 128 + rt * 8];
            float4 tf1 = *(const float4*)&Ts[kk * 128 + rt * 8 + 4];
            float4 ef0 = *(const float4*)&Es[kk * 128 + ce * 8];
            float4 ef1 = *(const float4*)&Es[kk * 128 + ce * 8 + 4];
            float a[8] = {tf0.x, tf0.y, tf0.z, tf0.w, tf1.x, tf1.y, tf1.z, tf1.w};
            float x[8] = {ef0.x, ef0.y, ef0.z, ef0.w, ef1.x, ef1.y, ef1.z, ef1.w};
#pragma unroll
            for (int i = 0; i < 8; ++i)
#pragma unroll
                for (int j = 0; j < 8; ++j)
                    acc[i][j] = __fadd_rn(acc[i][j], __fmul_rn(a[i], x[j]));
        }
    }

    float bias[8];
#pragma unroll
    for (int j = 0; j < 8; ++j) bias[j] = b_pw[e0 + ce * 8 + j];

#pragma unroll
    for (int i = 0; i < 8; ++i) {
        int tau = tg0 + rt * 8 + i;
        if (tau < tau1) {
            float* yrow = Yw + ((size_t)b * NTW + (tau - tau0)) * D_DIM + e0 + ce * 8;
#pragma unroll
            for (int j = 0; j < 8; ++j)
                yrow[j] = __fadd_rn(acc[i][j], bias[j]);
        }
    }
}

// ---------------------------------------------------------------------------
// K2: depthwise conv, f32, strict k-ascending, no FMA, zero padding.
// (byte-identical to round 5 — proven bit-exact)
// ---------------------------------------------------------------------------
__global__ __launch_bounds__(512, 1)
void dw_conv(const float* __restrict__ Yw, const float* __restrict__ w_dw,
             float* __restrict__ Zw, int t0, int tau0, int NTW)
{
#pragma clang fp contract(off)
    const int d  = threadIdx.x;              // 0..511
    const int tb = blockIdx.x * 8;           // t offset within pass
    const int b  = blockIdx.y;

    float wd[K_W];
#pragma unroll
    for (int k = 0; k < K_W; ++k) wd[k] = w_dw[d * K_W + k];

    const float* ybase = Yw + (size_t)b * NTW * D_DIM + d;

    float yw[38];
#pragma unroll
    for (int i = 0; i < 38; ++i) {
        int tau = t0 + tb - PAD + i;
        yw[i] = (tau >= 0 && tau < T_DIM)
              ? ybase[(size_t)(tau - tau0) * D_DIM] : 0.0f;
    }

#pragma unroll
    for (int j = 0; j < 8; ++j) {
        float z = 0.0f;
#pragma unroll
        for (int k = 0; k < K_W; ++k)        // strict ascending k
            z = __fadd_rn(z, __fmul_rn(wd[k], yw[j + k]));
        Zw[((size_t)(tb + j) * B_DIM + b) * D_DIM + d] = z;
    }
}

// ---------------------------------------------------------------------------
// K3: EXACT sequential LIF scan + residual, f32, numpy op-for-op.
// REWRITTEN for latency: round 5's per-step `if (tn < L)` branch wrapped
// every prefetch load in its own control-flow region -> per-step waitcnt
// drain -> 740 cyc/step (378 us). Now: branch-free double buffer (2 x 16
// steps), unconditional clamped-index loads issued in 32-deep batches,
// load->use distance = 16 steps of ALU. Arithmetic bit-identical.
// ---------------------------------------------------------------------------
__global__ __launch_bounds__(64, 1)
void lif_scan(const float* __restrict__ Zw, const float* __restrict__ inp,
              float* __restrict__ out, float* __restrict__ vst,
              int t0, int L, int first)
{
#pragma clang fp contract(off)
    const int lane = threadIdx.x;
    const int b    = blockIdx.x >> 3;                 // 0..15
    const int d    = ((blockIdx.x & 7) << 6) + lane;  // 0..511
    const int gi   = b * D_DIM + d;

    float v = first ? 0.0f : vst[gi];

    const float* zp = Zw + (size_t)b * D_DIM + d;
    const float* ip = inp + ((size_t)t0 * B_DIM + b) * D_DIM + d;
    float*       op = out + ((size_t)t0 * B_DIM + b) * D_DIM + d;
    const size_t st = (size_t)B_DIM * D_DIM;
    const int Lm1 = L - 1;

    float zb0[16], xb0[16], zb1[16], xb1[16];

#pragma unroll
    for (int j = 0; j < 16; ++j) {           // chunk 0 (t=0..15; L>=32)
        zb0[j] = zp[(size_t)j * st];
        xb0[j] = ip[(size_t)j * st];
    }

    for (int tb = 0; tb < L; tb += 32) {     // L is a multiple of 32
#pragma unroll
        for (int j = 0; j < 16; ++j) {       // issue chunk tb+16 (clamped)
            int t = tb + 16 + j; t = (t > Lm1) ? Lm1 : t;
            zb1[j] = zp[(size_t)t * st];
            xb1[j] = ip[(size_t)t * st];
        }
#pragma unroll
        for (int j = 0; j < 16; ++j) {       // consume chunk tb
            const int t = tb + j;
            v = __fadd_rn(__fmul_rn(v, 0.5f), zb0[j]);
            const bool sp = (v >= 1.0f);
            op[(size_t)t * st] = __fadd_rn(sp ? 1.0f : 0.0f, xb0[j]);
            v = __fmul_rn(v, sp ? 0.0f : 1.0f);   // mirrors np v*(1-s)
        }
#pragma unroll
        for (int j = 0; j < 16; ++j) {       // issue chunk tb+32 (clamped)
            int t = tb + 32 + j; t = (t > Lm1) ? Lm1 : t;
            zb0[j] = zp[(size_t)t * st];
            xb0[j] = ip[(size_t)t * st];
        }
#pragma unroll
        for (int j = 0; j < 16; ++j) {       // consume chunk tb+16
            const int t = tb + 16 + j;
            v = __fadd_rn(__fmul_rn(v, 0.5f), zb1[j]);
            const bool sp = (v >= 1.0f);
            op[(size_t)t * st] = __fadd_rn(sp ? 1.0f : 0.0f, xb1[j]);
            v = __fmul_rn(v, sp ? 0.0f : 1.0f);
        }
    }
    vst[gi] = v;
}

// ---------------------------------------------------------------------------
// Pass-windowed driver (f32 buffers: Y NTW rows + Z L rows + vst, row=32KB).
// L chosen from ws_size (launch-time constant -> deterministic).
// ---------------------------------------------------------------------------
extern "C" void kernel_launch(void* const* d_in, const int* in_sizes, int n_in,
                              void* d_out, int out_size, void* d_ws, size_t ws_size,
                              hipStream_t stream)
{
    const float* inp  = (const float*)d_in[0];   // (T,B,D)
    const float* w_pw = (const float*)d_in[1];   // (D,D)
    const float* b_pw = (const float*)d_in[2];   // (D)
    const float* w_dw = (const float*)d_in[3];   // (D,K)
    float* out = (float*)d_out;

    auto need = [](int L) -> size_t {
        int ntw = (L + 30 > T_DIM) ? T_DIM : (L + 30);
        return ((size_t)ntw + (size_t)L + 1) * (B_DIM * D_DIM * sizeof(float));
    };
    int L = 32;
    if      (ws_size >= need(1024)) L = 1024;
    else if (ws_size >= need(512))  L = 512;
    else if (ws_size >= need(256))  L = 256;
    else if (ws_size >= need(128))  L = 128;
    else if (ws_size >= need(64))   L = 64;

    const int NTWmax = (L + 30 > T_DIM) ? T_DIM : (L + 30);
    float* Yw  = (float*)d_ws;
    float* Zw  = Yw + (size_t)NTWmax * B_DIM * D_DIM;
    float* vst = Zw + (size_t)L * B_DIM * D_DIM;

    const int P = T_DIM / L;
    for (int p = 0; p < P; ++p) {
        const int t0   = p * L;
        const int t1   = t0 + L;
        const int tau0 = (t0 - PAD > 0) ? (t0 - PAD) : 0;
        const int tau1 = (t1 + PAD < T_DIM) ? (t1 + PAD) : T_DIM;
        const int NTW  = tau1 - tau0;

        dim3 g1(D_DIM / 128, (NTW + 127) / 128, B_DIM);
        pw_gemm<<<g1, 256, 0, stream>>>(inp, w_pw, b_pw, Yw, tau0, tau1, NTW);

        dim3 g2(L / 8, B_DIM);
        dw_conv<<<g2, 512, 0, stream>>>(Yw, w_dw, Zw, t0, tau0, NTW);

        lif_scan<<<128, 64, 0, stream>>>(Zw, inp, out, vst, t0, L, p == 0);
    }
}

// Round 7
// 200.188 us; speedup vs baseline: 2.6835x; 1.2140x over previous
//
#include <hip/hip_runtime.h>

#define T_DIM 1024
#define B_DIM 16
#define D_DIM 512
#define K_W   31
#define PAD   15

// ===========================================================================
// ALL numeric ops are f32 with NO fma contraction and numpy-sequential
// reduction order, to bit-match the harness's strict-sequential f32 np ref.
// Rounds 5/6 PASSED with absmax 0.0 — do NOT change rounding/order/precision:
// f64 accuracy FLIPS a borderline spike (rounds 1-4, absmax 0.998046875).
// ===========================================================================

// ---------------------------------------------------------------------------
// K1: pointwise GEMM, f32, strict d-ascending accumulation, no FMA.
// R7: Es tile skewed (off(e) = e + (e>>5)*4, row stride 144) to break the
// 4-way LDS bank conflict on the e-side ds_read_b128 (lanes at ce*8 dwords
// hit banks {0,8,16,24}; skew makes worst case 2-way = free per m136).
// Pure layout change — arithmetic order identical.
// ---------------------------------------------------------------------------
#define ES_STRIDE 144
__global__ __launch_bounds__(256, 2)
void pw_gemm(const float* __restrict__ inp, const float* __restrict__ w_pw,
             const float* __restrict__ b_pw, float* __restrict__ Yw,
             int tau0, int tau1, int NTW)
{
#pragma clang fp contract(off)
    __shared__ float Es[32 * ES_STRIDE];   // [k][skew(e_local)]
    __shared__ float Ts[32 * 128];         // [k][tau_local]

    const int tid = threadIdx.x;
    const int e0  = blockIdx.x * 128;
    int tg0 = tau0 + blockIdx.y * 128;           // tau tile base
    if (tg0 + 128 > tau1) {                      // shift last tile; overlap
        int s = tau1 - 128;                      // writes identical values
        tg0 = (s > tau0) ? s : tau0;
    }
    const int b  = blockIdx.z;
    const int rt = tid >> 4;                     // tau-sub 0..15
    const int ce = tid & 15;                     // e-sub   0..15
    const int eoff = ce * 8 + ((ce >> 2) << 2);  // skewed read base

    float acc[8][8];
#pragma unroll
    for (int i = 0; i < 8; ++i)
#pragma unroll
        for (int j = 0; j < 8; ++j) acc[i][j] = 0.0f;

    for (int k0 = 0; k0 < D_DIM; k0 += 32) {     // strict ascending d blocks
        float4 av[4], xv[4];
#pragma unroll
        for (int i = 0; i < 4; ++i) {
            int cid = tid + 256 * i;             // 0..1023
            int row = cid >> 3;                  // 0..127
            int kq  = cid & 7;
            int trow = tg0 + row;
            if (trow > T_DIM - 1) trow = T_DIM - 1;   // clamp; stores guarded
            av[i] = *(const float4*)&w_pw[(size_t)(e0 + row) * D_DIM + k0 + kq * 4];
            xv[i] = *(const float4*)&inp[(size_t)trow * (B_DIM * D_DIM)
                                         + (size_t)b * D_DIM + k0 + kq * 4];
        }
        __syncthreads();
#pragma unroll
        for (int i = 0; i < 4; ++i) {
            int cid = tid + 256 * i;
            int row = cid >> 3;
            int kq  = cid & 7;
            int srow = row + ((row >> 5) << 2);  // skew(e)
            Es[(kq * 4 + 0) * ES_STRIDE + srow] = av[i].x;
            Es[(kq * 4 + 1) * ES_STRIDE + srow] = av[i].y;
            Es[(kq * 4 + 2) * ES_STRIDE + srow] = av[i].z;
            Es[(kq * 4 + 3) * ES_STRIDE + srow] = av[i].w;
            Ts[(kq * 4 + 0) * 128 + row] = xv[i].x;
            Ts[(kq * 4 + 1) * 128 + row] = xv[i].y;
            Ts[(kq * 4 + 2) * 128 + row] = xv[i].z;
            Ts[(kq * 4 + 3) * 128 + row] = xv[i].w;
        }
        __syncthreads();

#pragma unroll 8
        for (int kk = 0; kk < 32; ++kk) {        // strict ascending d
            float4 tf0 = *(const float4*)&Ts[kk * 128 + rt * 8];
            float4 tf1 = *(const float4*)&Ts[kk * 128 + rt * 8 + 4];
            float4 ef0 = *(const float4*)&Es[kk * ES_STRIDE + eoff];
            float4 ef1 = *(const float4*)&Es[kk * ES_STRIDE + eoff + 4];
            float a[8] = {tf0.x, tf0.y, tf0.z, tf0.w, tf1.x, tf1.y, tf1.z, tf1.w};
            float x[8] = {ef0.x, ef0.y, ef0.z, ef0.w, ef1.x, ef1.y, ef1.z, ef1.w};
#pragma unroll
            for (int i = 0; i < 8; ++i)
#pragma unroll
                for (int j = 0; j < 8; ++j)
                    acc[i][j] = __fadd_rn(acc[i][j], __fmul_rn(a[i], x[j]));
        }
    }

    float bias[8];
#pragma unroll
    for (int j = 0; j < 8; ++j) bias[j] = b_pw[e0 + ce * 8 + j];

#pragma unroll
    for (int i = 0; i < 8; ++i) {
        int tau = tg0 + rt * 8 + i;
        if (tau < tau1) {
            float* yrow = Yw + ((size_t)b * NTW + (tau - tau0)) * D_DIM + e0 + ce * 8;
#pragma unroll
            for (int j = 0; j < 8; ++j)
                yrow[j] = __fadd_rn(acc[i][j], bias[j]);
        }
    }
}

// ---------------------------------------------------------------------------
// K2: depthwise conv, f32, strict k-ascending, no FMA, zero padding.
// (byte-identical to rounds 5/6 — proven bit-exact)
// ---------------------------------------------------------------------------
__global__ __launch_bounds__(512, 1)
void dw_conv(const float* __restrict__ Yw, const float* __restrict__ w_dw,
             float* __restrict__ Zw, int t0, int tau0, int NTW)
{
#pragma clang fp contract(off)
    const int d  = threadIdx.x;              // 0..511
    const int tb = blockIdx.x * 8;           // t offset within pass
    const int b  = blockIdx.y;

    float wd[K_W];
#pragma unroll
    for (int k = 0; k < K_W; ++k) wd[k] = w_dw[d * K_W + k];

    const float* ybase = Yw + (size_t)b * NTW * D_DIM + d;

    float yw[38];
#pragma unroll
    for (int i = 0; i < 38; ++i) {
        int tau = t0 + tb - PAD + i;
        yw[i] = (tau >= 0 && tau < T_DIM)
              ? ybase[(size_t)(tau - tau0) * D_DIM] : 0.0f;
    }

#pragma unroll
    for (int j = 0; j < 8; ++j) {
        float z = 0.0f;
#pragma unroll
        for (int k = 0; k < K_W; ++k)        // strict ascending k
            z = __fadd_rn(z, __fmul_rn(wd[k], yw[j + k]));
        Zw[((size_t)(tb + j) * B_DIM + b) * D_DIM + d] = z;
    }
}

// ---------------------------------------------------------------------------
// K3: EXACT sequential LIF scan, f32, numpy op-for-op. R7: z-loads ONLY,
// spikes emitted as packed u32 bitmasks (bit j = step tb+j), 32-step double
// buffer. No x-loads / out-stores here (moved to spike_add) -> VMEM queue is
// pure batched loads + 1 store/32 steps. Arithmetic bit-identical.
// ---------------------------------------------------------------------------
__global__ __launch_bounds__(64, 1)
void lif_scan(const float* __restrict__ Zw, unsigned* __restrict__ sw,
              float* __restrict__ vst, int L, int first)
{
#pragma clang fp contract(off)
    const int lane = threadIdx.x;
    const int b    = blockIdx.x >> 3;                 // 0..15
    const int d    = ((blockIdx.x & 7) << 6) + lane;  // 0..511
    const int gi   = b * D_DIM + d;

    float v = first ? 0.0f : vst[gi];

    const float* zp = Zw + (size_t)b * D_DIM + d;
    unsigned*    wp = sw + gi;                        // + (t>>5)*B*D
    const size_t st = (size_t)B_DIM * D_DIM;
    const int Lm1 = L - 1;

    float zA[32], zB[32];
#pragma unroll
    for (int j = 0; j < 32; ++j) zA[j] = zp[(size_t)j * st];   // L >= 64

    for (int tb = 0; tb < L; tb += 64) {     // L is a multiple of 64
#pragma unroll
        for (int j = 0; j < 32; ++j) {       // issue steps tb+32..tb+63
            int t = tb + 32 + j; t = (t > Lm1) ? Lm1 : t;
            zB[j] = zp[(size_t)t * st];
        }
        unsigned m = 0;
#pragma unroll
        for (int j = 0; j < 32; ++j) {       // consume steps tb..tb+31
            v = __fadd_rn(__fmul_rn(v, 0.5f), zA[j]);
            const bool sp = (v >= 1.0f);
            m |= (sp ? (1u << j) : 0u);
            v = __fmul_rn(v, sp ? 0.0f : 1.0f);   // mirrors np v*(1-s)
        }
        wp[(size_t)(tb >> 5) * st] = m;
#pragma unroll
        for (int j = 0; j < 32; ++j) {       // issue steps tb+64..tb+95
            int t = tb + 64 + j; t = (t > Lm1) ? Lm1 : t;
            zA[j] = zp[(size_t)t * st];
        }
        m = 0;
#pragma unroll
        for (int j = 0; j < 32; ++j) {       // consume steps tb+32..tb+63
            v = __fadd_rn(__fmul_rn(v, 0.5f), zB[j]);
            const bool sp = (v >= 1.0f);
            m |= (sp ? (1u << j) : 0u);
            v = __fmul_rn(v, sp ? 0.0f : 1.0f);
        }
        wp[(size_t)((tb >> 5) + 1) * st] = m;
    }
    vst[gi] = v;
}

// ---------------------------------------------------------------------------
// K4: out[t,b,d] = fl(s + inp[t,b,d]), s = spike bit. Fully parallel,
// float4/uint4 vectorized, grid-stride. s in {0,1} exactly -> bit-exact.
// ---------------------------------------------------------------------------
__global__ __launch_bounds__(256, 4)
void spike_add(const unsigned* __restrict__ sw, const float* __restrict__ inp,
               float* __restrict__ out, int t0, int L)
{
#pragma clang fp contract(off)
    const size_t n4 = (size_t)L * B_DIM * D_DIM / 4;
    const float4* ip = (const float4*)(inp + (size_t)t0 * B_DIM * D_DIM);
    float4*       op = (float4*)(out + (size_t)t0 * B_DIM * D_DIM);
    const size_t stride = (size_t)gridDim.x * blockDim.x;

    for (size_t i = (size_t)blockIdx.x * blockDim.x + threadIdx.x;
         i < n4; i += stride) {
        const size_t e    = i * 4;           // element index within pass
        const size_t trel = e >> 13;         // / (B*D = 8192)
        const size_t r    = e & 8191;
        const uint4 w = *(const uint4*)(sw + ((trel >> 5) << 13) + r);
        const unsigned sh = (unsigned)trel & 31u;
        const float4 x = ip[i];
        float4 o;
        o.x = __fadd_rn((float)((w.x >> sh) & 1u), x.x);
        o.y = __fadd_rn((float)((w.y >> sh) & 1u), x.y);
        o.z = __fadd_rn((float)((w.z >> sh) & 1u), x.z);
        o.w = __fadd_rn((float)((w.w >> sh) & 1u), x.w);
        op[i] = o;
    }
}

// ---------------------------------------------------------------------------
// Pass-windowed driver. Spike words overlay the (dead-after-dw_conv) Yw
// region — no extra ws needed. L from ws_size (launch-time constant).
// ---------------------------------------------------------------------------
extern "C" void kernel_launch(void* const* d_in, const int* in_sizes, int n_in,
                              void* d_out, int out_size, void* d_ws, size_t ws_size,
                              hipStream_t stream)
{
    const float* inp  = (const float*)d_in[0];   // (T,B,D)
    const float* w_pw = (const float*)d_in[1];   // (D,D)
    const float* b_pw = (const float*)d_in[2];   // (D)
    const float* w_dw = (const float*)d_in[3];   // (D,K)
    float* out = (float*)d_out;

    auto need = [](int L) -> size_t {
        int ntw = (L + 30 > T_DIM) ? T_DIM : (L + 30);
        return ((size_t)ntw + (size_t)L + 1) * (B_DIM * D_DIM * sizeof(float));
    };
    int L = 64;
    if      (ws_size >= need(1024)) L = 1024;
    else if (ws_size >= need(512))  L = 512;
    else if (ws_size >= need(256))  L = 256;
    else if (ws_size >= need(128))  L = 128;

    const int NTWmax = (L + 30 > T_DIM) ? T_DIM : (L + 30);
    float* Yw  = (float*)d_ws;
    float* Zw  = Yw + (size_t)NTWmax * B_DIM * D_DIM;
    float* vst = Zw + (size_t)L * B_DIM * D_DIM;
    unsigned* sw = (unsigned*)Yw;                // overlay: Yw dead after dw_conv

    const int P = T_DIM / L;
    for (int p = 0; p < P; ++p) {
        const int t0   = p * L;
        const int t1   = t0 + L;
        const int tau0 = (t0 - PAD > 0) ? (t0 - PAD) : 0;
        const int tau1 = (t1 + PAD < T_DIM) ? (t1 + PAD) : T_DIM;
        const int NTW  = tau1 - tau0;

        dim3 g1(D_DIM / 128, (NTW + 127) / 128, B_DIM);
        pw_gemm<<<g1, 256, 0, stream>>>(inp, w_pw, b_pw, Yw, tau0, tau1, NTW);

        dim3 g2(L / 8, B_DIM);
        dw_conv<<<g2, 512, 0, stream>>>(Yw, w_dw, Zw, t0, tau0, NTW);

        lif_scan<<<128, 64, 0, stream>>>(Zw, sw, vst, L, p == 0);

        spike_add<<<2048, 256, 0, stream>>>(sw, inp, out, t0, L);
    }
}